// Round 2
// baseline (808.063 us; speedup 1.0000x reference)
//
#include <hip/hip_runtime.h>
#include <cstdint>
#include <cstddef>

// ============================================================================
// DualStateLinearAttention on MI355X — round 1
// Crash fix: workspace cut 269MB -> ~105MB + graceful fallback if ws_size is
// still too small (zero-fills d_out so the bench reports absmax instead of
// core-dumping — a diagnostic, not a pass).
//
// Pipeline (all on `stream`):
//   cvt X->bf16
//   for W in {Wq,Wk,Wv,Wg1,Wg2}: cvt W->Wcur; GEMM (gates get logsigmoid epi)
//   for e in {0,1}:   (temporal reuse: U/S scratch lives in d_out, 33.5MB exact)
//     s1: per chunk U = K-hat^T V  -> d_out        (K-hat = k*exp(B-b))
//     s2: sequential chunk combine -> S_n in place (state BEFORE chunk n)
//     s3a: intra-chunk causal (Q-hat K-hat2^T ⊙ mask) V  -> attn (w_e folded)
//     s3b: inter-chunk Q-hat @ S_n                        -> attn +=
//   cvt Wo->Wcur; GEMM attn @ Wo^T -> d_out (fp32)
//
// attn reuses Xb (dead after the 5 projection GEMMs). Chunk math: b = incl.
// in-chunk cumsum of g (g<=0); exponents bounded (|B| <~ 6.5 at C=64) so
// exp factorization is fp32/bf16-safe.
// ============================================================================

#define BB     2
#define SEQ    2048
#define HIDN   2048
#define NH     16
#define DD     128
#define CHUNK  64
#define NCHUNK (SEQ / CHUNK)   // 32
#define NBH    (BB * NH)       // 32
static constexpr float QSCALE = 0.08838834764831845f;  // 128^-0.5

typedef __bf16 bf16_t;
typedef short  short8 __attribute__((ext_vector_type(8)));  // MFMA A/B frag
typedef __bf16 bf16x8 __attribute__((ext_vector_type(8)));
typedef __bf16 bf16x4 __attribute__((ext_vector_type(4)));
typedef float  f32x4  __attribute__((ext_vector_type(4)));

__device__ __forceinline__ void gload_lds16(const void* g, void* l) {
  __builtin_amdgcn_global_load_lds(
      (__attribute__((address_space(1))) unsigned int*)g,
      (__attribute__((address_space(3))) unsigned int*)l, 16, 0, 0);
}

// ---------------------------------------------------------------------------
// bf16 MFMA GEMM:  C[4096,2048] = A[4096,2048] @ Bw[2048,2048]^T   (m97 style)
// EPI: 0 = bf16 store, 1 = gate epilogue (bias + logsigmoid/16, clamp), 2 = f32
// ---------------------------------------------------------------------------
template <int EPI>
__global__ __launch_bounds__(256) void k_gemm(const bf16_t* __restrict__ A,
                                              const bf16_t* __restrict__ Bw,
                                              const float*  __restrict__ bias,
                                              bf16_t* __restrict__ outb,
                                              float*  __restrict__ outf) {
  __shared__ bf16_t As[128 * 32];  // [m][k] rows of 64B
  __shared__ bf16_t Bs[128 * 32];  // [n][k]
  const int tm   = blockIdx.x * 128;
  const int tn   = blockIdx.y * 128;
  const int wave = threadIdx.x >> 6;
  const int lane = threadIdx.x & 63;
  const int wm   = (wave >> 1) * 64;
  const int wn   = (wave & 1) * 64;
  const int qd   = lane >> 4;
  const int l16  = lane & 15;

  // tile = 128 rows x 64B = 512 16B-chunks; chunk c -> LDS byte offset c*16
  const int c0 = (wave * 2 + 0) * 64 + lane;
  const int c1 = (wave * 2 + 1) * 64 + lane;
  const bf16_t* ga0 = A  + (size_t)(tm + (c0 >> 2)) * HIDN + (c0 & 3) * 8;
  const bf16_t* ga1 = A  + (size_t)(tm + (c1 >> 2)) * HIDN + (c1 & 3) * 8;
  const bf16_t* gb0 = Bw + (size_t)(tn + (c0 >> 2)) * HIDN + (c0 & 3) * 8;
  const bf16_t* gb1 = Bw + (size_t)(tn + (c1 >> 2)) * HIDN + (c1 & 3) * 8;
  bf16_t* la0 = &As[(wave * 2 + 0) * 512];  // wave-uniform LDS bases
  bf16_t* la1 = &As[(wave * 2 + 1) * 512];
  bf16_t* lb0 = &Bs[(wave * 2 + 0) * 512];
  bf16_t* lb1 = &Bs[(wave * 2 + 1) * 512];

  f32x4 acc[4][4];
#pragma unroll
  for (int i = 0; i < 4; i++)
#pragma unroll
    for (int j = 0; j < 4; j++) acc[i][j] = (f32x4){0.f, 0.f, 0.f, 0.f};

  for (int k0 = 0; k0 < HIDN; k0 += 32) {
    gload_lds16(ga0, la0); gload_lds16(ga1, la1);
    gload_lds16(gb0, lb0); gload_lds16(gb1, lb1);
    ga0 += 32; ga1 += 32; gb0 += 32; gb1 += 32;
    __syncthreads();
    short8 af[4], bfv[4];
#pragma unroll
    for (int t = 0; t < 4; t++)
      af[t] = *(const short8*)&As[(wm + t * 16 + l16) * 32 + qd * 8];
#pragma unroll
    for (int t = 0; t < 4; t++)
      bfv[t] = *(const short8*)&Bs[(wn + t * 16 + l16) * 32 + qd * 8];
#pragma unroll
    for (int i = 0; i < 4; i++)
#pragma unroll
      for (int j = 0; j < 4; j++)
        acc[i][j] = __builtin_amdgcn_mfma_f32_16x16x32_bf16(af[i], bfv[j],
                                                            acc[i][j], 0, 0, 0);
    __syncthreads();
  }

#pragma unroll
  for (int i = 0; i < 4; i++)
#pragma unroll
    for (int j = 0; j < 4; j++)
#pragma unroll
      for (int r = 0; r < 4; r++) {
        const int row = tm + wm + i * 16 + qd * 4 + r;  // C/D: row=quad*4+reg
        const int col = tn + wn + j * 16 + l16;         //      col=lane&15
        float v = acc[i][j][r];
        if (EPI == 1) {
          v += bias[col];
          const float ls = fminf(v, 0.f) - log1pf(__expf(-fabsf(v)));
          v = fmaxf(ls * 0.0625f, -50.f);
        }
        if (EPI == 2) outf[(size_t)row * HIDN + col] = v;
        else          outb[(size_t)row * HIDN + col] = (bf16_t)v;
      }
}

// ---------------------------------------------------------------------------
__global__ __launch_bounds__(256) void k_cvt(const float* __restrict__ src,
                                             bf16_t* __restrict__ dst, int n) {
  const int idx = (blockIdx.x * 256 + threadIdx.x) * 4;
  if (idx < n) {
    const float4 f = *(const float4*)(src + idx);
    bf16x4 o;
    o[0] = (bf16_t)f.x; o[1] = (bf16_t)f.y; o[2] = (bf16_t)f.z; o[3] = (bf16_t)f.w;
    *(bf16x4*)(dst + idx) = o;
  }
}

__global__ __launch_bounds__(256) void k_zero(float* __restrict__ out) {
  out[(size_t)blockIdx.x * 256 + threadIdx.x] = 0.f;
}

// ---------------------------------------------------------------------------
// S1: per (chunk n, bh):  U = K-hat^T V ; Btot[d] = chunk gate sum
// ---------------------------------------------------------------------------
__global__ __launch_bounds__(256) void k_s1(
    const bf16_t* __restrict__ Kb, const bf16_t* __restrict__ Vb,
    const bf16_t* __restrict__ G, bf16_t* __restrict__ US,
    float* __restrict__ Btot) {
  const int n = blockIdx.x, bh = blockIdx.y;
  const int b = bh >> 4, h = bh & 15;
  const int tid = threadIdx.x;
  __shared__ bf16_t kh[CHUNK][DD];   // k-hat [s][d]
  __shared__ bf16_t vsh[CHUNK][DD];  // v     [s][d]
  const size_t base = ((size_t)(b * SEQ + n * CHUNK)) * HIDN + h * DD;

  for (int i = tid; i < CHUNK * DD / 8; i += 256) {
    const int t = i >> 4, d0 = (i & 15) * 8;
    *(bf16x8*)&vsh[t][d0] = *(const bf16x8*)&Vb[base + (size_t)t * HIDN + d0];
  }
  if (tid < DD) {
    const int d = tid;
    float c = 0.f;
    for (int t = 0; t < CHUNK; t++) c += (float)G[base + (size_t)t * HIDN + d];
    const float Bt = c;
    Btot[((size_t)bh * NCHUNK + n) * DD + d] = Bt;
    float c2 = 0.f;
    for (int t = 0; t < CHUNK; t++) {
      c2 += (float)G[base + (size_t)t * HIDN + d];
      const float kv = (float)Kb[base + (size_t)t * HIDN + d];
      kh[t][d] = (bf16_t)(kv * __expf(Bt - c2));  // exponent <= 0
    }
  }
  __syncthreads();

  const int dk0 = (tid >> 4) * 8, dv0 = (tid & 15) * 8;
  float acc[8][8] = {};
  for (int s = 0; s < CHUNK; s++) {
    const bf16x8 av = *(const bf16x8*)&kh[s][dk0];
    const bf16x8 vv = *(const bf16x8*)&vsh[s][dv0];
#pragma unroll
    for (int i = 0; i < 8; i++)
#pragma unroll
      for (int j = 0; j < 8; j++)
        acc[i][j] = fmaf((float)av[i], (float)vv[j], acc[i][j]);
  }
  bf16_t* Uo = US + ((size_t)bh * NCHUNK + n) * (size_t)(DD * DD);
#pragma unroll
  for (int i = 0; i < 8; i++) {
    bf16x8 o;
#pragma unroll
    for (int j = 0; j < 8; j++) o[j] = (bf16_t)acc[i][j];
    *(bf16x8*)&Uo[(size_t)(dk0 + i) * DD + dv0] = o;
  }
}

// ---------------------------------------------------------------------------
// S2: sequential chunk combine; stores S_n (state BEFORE chunk n) over U_n.
// ---------------------------------------------------------------------------
__global__ __launch_bounds__(256) void k_s2(bf16_t* __restrict__ US,
                                            const float* __restrict__ Btot) {
  const int dg = blockIdx.x, bh = blockIdx.y;
  const int d = dg * 8 + (threadIdx.x >> 5);
  const int c0 = (threadIdx.x & 31) * 4;
  float st[4] = {0.f, 0.f, 0.f, 0.f};
  for (int n = 0; n < NCHUNK; n++) {
    bf16_t* p = US + ((size_t)bh * NCHUNK + n) * (size_t)(DD * DD) + d * DD + c0;
    const bf16x4 u = *(const bf16x4*)p;
    const float eB = __expf(Btot[((size_t)bh * NCHUNK + n) * DD + d]);
    bf16x4 sv;
#pragma unroll
    for (int j = 0; j < 4; j++) sv[j] = (bf16_t)st[j];
    *(bf16x4*)p = sv;
#pragma unroll
    for (int j = 0; j < 4; j++) st[j] = st[j] * eB + (float)u[j];
  }
}

// ---------------------------------------------------------------------------
// S3a: intra-chunk causal, softmax weight w_e folded into q-hat.
// ACC=0: attn = result; ACC=1: attn += result.
// ---------------------------------------------------------------------------
template <int ACC>
__global__ __launch_bounds__(256) void k_s3a(
    const bf16_t* __restrict__ Qb, const bf16_t* __restrict__ Kb,
    const bf16_t* __restrict__ Vb, const bf16_t* __restrict__ G,
    const float* __restrict__ alpha, const int e, bf16_t* __restrict__ attn) {
  const int n = blockIdx.x, bh = blockIdx.y;
  const int b = bh >> 4, h = bh & 15;
  const int tid = threadIdx.x;
  __shared__ bf16_t qh[DD][CHUNK];    // q-hat^T [d][t]   (w_e*scale*exp(b))
  __shared__ bf16_t kh[DD][CHUNK];    // k-hat2^T [d][s]  (exp(-b))
  __shared__ bf16_t vsh[CHUNK][DD];   // v [s][d]
  __shared__ bf16_t At[CHUNK][CHUNK]; // A^T [s][t]
  const size_t base = ((size_t)(b * SEQ + n * CHUNK)) * HIDN + h * DD;
  const float mx = fmaxf(alpha[0], alpha[1]);
  const float x0 = __expf(alpha[0] - mx), x1 = __expf(alpha[1] - mx);
  const float w = (e ? x1 : x0) / (x0 + x1);

  for (int i = tid; i < CHUNK * DD / 8; i += 256) {
    const int t = i >> 4, d0 = (i & 15) * 8;
    *(bf16x8*)&vsh[t][d0] = *(const bf16x8*)&Vb[base + (size_t)t * HIDN + d0];
  }
  if (tid < DD) {
    const int d = tid;
    const float wsc = w * QSCALE;
    float c = 0.f;
    for (int t = 0; t < CHUNK; t++) {
      c += (float)G[base + (size_t)t * HIDN + d];
      qh[d][t] = (bf16_t)((float)Qb[base + (size_t)t * HIDN + d] * wsc * __expf(c));
      kh[d][t] = (bf16_t)((float)Kb[base + (size_t)t * HIDN + d] * __expf(-c));
    }
  }
  __syncthreads();

  {  // A^T with causal mask
    const int t0 = (tid >> 4) * 4, s0 = (tid & 15) * 4;
    float a[4][4] = {};
#pragma unroll 4
    for (int d = 0; d < DD; d++) {
      const bf16x4 qv = *(const bf16x4*)&qh[d][t0];
      const bf16x4 kv = *(const bf16x4*)&kh[d][s0];
#pragma unroll
      for (int i = 0; i < 4; i++)
#pragma unroll
        for (int j = 0; j < 4; j++)
          a[i][j] = fmaf((float)qv[i], (float)kv[j], a[i][j]);
    }
#pragma unroll
    for (int j = 0; j < 4; j++) {
      bf16x4 o;
#pragma unroll
      for (int i = 0; i < 4; i++)
        o[i] = (t0 + i >= s0 + j) ? (bf16_t)a[i][j] : (bf16_t)0.f;
      *(bf16x4*)&At[s0 + j][t0] = o;
    }
  }
  __syncthreads();

  {  // o_intra = A V
    const int t0 = (tid >> 4) * 4, v0 = (tid & 15) * 8;
    float o[4][8] = {};
#pragma unroll 2
    for (int s = 0; s < CHUNK; s++) {
      const bf16x4 av = *(const bf16x4*)&At[s][t0];
      const bf16x8 vv = *(const bf16x8*)&vsh[s][v0];
#pragma unroll
      for (int i = 0; i < 4; i++)
#pragma unroll
        for (int j = 0; j < 8; j++)
          o[i][j] = fmaf((float)av[i], (float)vv[j], o[i][j]);
    }
#pragma unroll
    for (int i = 0; i < 4; i++) {
      bf16_t* p = &attn[base + (size_t)(t0 + i) * HIDN + v0];
      bf16x8 ov;
      if (ACC) {
        const bf16x8 cur = *(const bf16x8*)p;
#pragma unroll
        for (int j = 0; j < 8; j++) ov[j] = (bf16_t)((float)cur[j] + o[i][j]);
      } else {
#pragma unroll
        for (int j = 0; j < 8; j++) ov[j] = (bf16_t)o[i][j];
      }
      *(bf16x8*)p = ov;
    }
  }
}

// ---------------------------------------------------------------------------
// S3b: inter-chunk  attn += (w_e * q*scale*exp(b)) @ S_n
// ---------------------------------------------------------------------------
__global__ __launch_bounds__(256) void k_s3b(
    const bf16_t* __restrict__ Qb, const bf16_t* __restrict__ G,
    const bf16_t* __restrict__ US, const float* __restrict__ alpha,
    const int e, bf16_t* __restrict__ attn) {
  const int n = blockIdx.x, bh = blockIdx.y;
  const int b = bh >> 4, h = bh & 15;
  const int tid = threadIdx.x;
  __shared__ bf16_t qh[DD][CHUNK];  // q-hat^T [d][t]
  __shared__ bf16_t Ssh[DD][DD];    // S_n [d][v]
  const size_t base = ((size_t)(b * SEQ + n * CHUNK)) * HIDN + h * DD;
  const float mx = fmaxf(alpha[0], alpha[1]);
  const float x0 = __expf(alpha[0] - mx), x1 = __expf(alpha[1] - mx);
  const float w = (e ? x1 : x0) / (x0 + x1);

  const bf16_t* Sp = US + ((size_t)bh * NCHUNK + n) * (size_t)(DD * DD);
  for (int i = tid; i < DD * DD / 8; i += 256) {
    const int d = i >> 4, c0 = (i & 15) * 8;
    *(bf16x8*)&Ssh[d][c0] = *(const bf16x8*)&Sp[(size_t)d * DD + c0];
  }
  if (tid < DD) {
    const int d = tid;
    const float wsc = w * QSCALE;
    float c = 0.f;
    for (int t = 0; t < CHUNK; t++) {
      c += (float)G[base + (size_t)t * HIDN + d];
      qh[d][t] = (bf16_t)((float)Qb[base + (size_t)t * HIDN + d] * wsc * __expf(c));
    }
  }
  __syncthreads();

  const int t0 = (tid >> 4) * 4, v0 = (tid & 15) * 8;
  float o[4][8] = {};
#pragma unroll 4
  for (int d = 0; d < DD; d++) {
    const bf16x4 qv = *(const bf16x4*)&qh[d][t0];
    const bf16x8 sv = *(const bf16x8*)&Ssh[d][v0];
#pragma unroll
    for (int i = 0; i < 4; i++)
#pragma unroll
      for (int j = 0; j < 8; j++)
        o[i][j] = fmaf((float)qv[i], (float)sv[j], o[i][j]);
  }
#pragma unroll
  for (int i = 0; i < 4; i++) {
    bf16_t* p = &attn[base + (size_t)(t0 + i) * HIDN + v0];
    const bf16x8 cur = *(const bf16x8*)p;
    bf16x8 ov;
#pragma unroll
    for (int j = 0; j < 8; j++) ov[j] = (bf16_t)((float)cur[j] + o[i][j]);
    *(bf16x8*)p = ov;
  }
}

// ---------------------------------------------------------------------------
extern "C" void kernel_launch(void* const* d_in, const int* in_sizes, int n_in,
                              void* d_out, int out_size, void* d_ws,
                              size_t ws_size, hipStream_t stream) {
  const float* hid  = (const float*)d_in[0];
  const float* wq   = (const float*)d_in[1];
  const float* wk   = (const float*)d_in[2];
  const float* wv   = (const float*)d_in[3];
  const float* wo   = (const float*)d_in[4];
  const float* wg1  = (const float*)d_in[5];
  const float* bg1  = (const float*)d_in[6];
  const float* wg2  = (const float*)d_in[7];
  const float* bg2  = (const float*)d_in[8];
  const float* alph = (const float*)d_in[9];
  float* out = (float*)d_out;
  (void)in_sizes; (void)n_in; (void)out_size;

  char* ws = (char*)d_ws;
  size_t off = 0;
  auto alloc = [&](size_t bytes) -> void* {
    void* p = ws + off;
    off += (bytes + 255) & ~(size_t)255;
    return p;
  };
  const size_t NEL = (size_t)BB * SEQ * HIDN;  // 8,388,608
  const size_t WEL = (size_t)HIDN * HIDN;      // 4,194,304
  bf16_t* Xb   = (bf16_t*)alloc(NEL * 2);      // X bf16; reused as attn later
  bf16_t* Wcur = (bf16_t*)alloc(WEL * 2);      // one converted weight at a time
  bf16_t* Qb   = (bf16_t*)alloc(NEL * 2);
  bf16_t* Kb   = (bf16_t*)alloc(NEL * 2);
  bf16_t* Vb   = (bf16_t*)alloc(NEL * 2);
  bf16_t* G1b  = (bf16_t*)alloc(NEL * 2);
  bf16_t* G2b  = (bf16_t*)alloc(NEL * 2);
  float*  Btot = (float*) alloc((size_t)NBH * NCHUNK * DD * 4);
  // U/S chunk-state scratch lives in d_out: NBH*NCHUNK*DD*DD bf16 = 33,554,432B
  // == out_size*4 exactly; final GEMM overwrites d_out afterwards.
  bf16_t* US = (bf16_t*)d_out;

  if (off > ws_size) {  // diagnostic fallback: fail cleanly, don't page-fault
    k_zero<<<dim3((unsigned)(NEL / 256)), 256, 0, stream>>>(out);
    return;
  }

  const dim3 gg(32, 16), gs(NCHUNK, NBH), g2(16, NBH);
  k_cvt<<<8192, 256, 0, stream>>>(hid, Xb, (int)NEL);

  k_cvt<<<4096, 256, 0, stream>>>(wq, Wcur, (int)WEL);
  k_gemm<0><<<gg, 256, 0, stream>>>(Xb, Wcur, nullptr, Qb, nullptr);
  k_cvt<<<4096, 256, 0, stream>>>(wk, Wcur, (int)WEL);
  k_gemm<0><<<gg, 256, 0, stream>>>(Xb, Wcur, nullptr, Kb, nullptr);
  k_cvt<<<4096, 256, 0, stream>>>(wv, Wcur, (int)WEL);
  k_gemm<0><<<gg, 256, 0, stream>>>(Xb, Wcur, nullptr, Vb, nullptr);
  k_cvt<<<4096, 256, 0, stream>>>(wg1, Wcur, (int)WEL);
  k_gemm<1><<<gg, 256, 0, stream>>>(Xb, Wcur, bg1, G1b, nullptr);
  k_cvt<<<4096, 256, 0, stream>>>(wg2, Wcur, (int)WEL);
  k_gemm<1><<<gg, 256, 0, stream>>>(Xb, Wcur, bg2, G2b, nullptr);

  for (int e = 0; e < 2; e++) {
    const bf16_t* G = e ? G2b : G1b;
    k_s1<<<gs, 256, 0, stream>>>(Kb, Vb, G, US, Btot);
    k_s2<<<g2, 256, 0, stream>>>(US, Btot);
    if (e == 0)
      k_s3a<0><<<gs, 256, 0, stream>>>(Qb, Kb, Vb, G, alph, e, Xb);
    else
      k_s3a<1><<<gs, 256, 0, stream>>>(Qb, Kb, Vb, G, alph, e, Xb);
    k_s3b<<<gs, 256, 0, stream>>>(Qb, G, US, alph, e, Xb);
  }

  k_cvt<<<4096, 256, 0, stream>>>(wo, Wcur, (int)WEL);
  k_gemm<2><<<gg, 256, 0, stream>>>(Xb, Wcur, nullptr, nullptr, out);
}

// Round 3
// 617.910 us; speedup vs baseline: 1.3077x; 1.3077x over previous
//
#include <hip/hip_runtime.h>
#include <cstdint>
#include <cstddef>

// ============================================================================
// DualStateLinearAttention on MI355X — round 2
//  R1 post-mortem: proj GEMMs grid-starved (512 blocks, occ 19%), scans ~343us
//  of VALU fp32. This round: (1) fuse 5 proj GEMMs into one grid.z=5 dispatch
//  (weights Wq..Wg1 staged bf16 in d_out = exactly 4x8.39MB; Wg2 in ws),
//  (2) MFMA-ize scans: s1 computes U^T=(K-hat^T V)^T via mfma so s2's states
//  S^T are directly the B-operand of the inter-chunk Q-hat@S (read from global
//  as fragments), s3a+s3b fused (shared accumulators, one attn write).
//  XOR-swizzled LDS tiles keep ds_read_b128 frag reads ~conflict-free.
// ============================================================================

#define BB     2
#define SEQ    2048
#define HIDN   2048
#define NH     16
#define DD     128
#define CHUNK  64
#define NCHUNK (SEQ / CHUNK)   // 32
#define NBH    (BB * NH)       // 32
#define NELC   8388608         // BB*SEQ*HIDN
#define WELC   4194304         // HIDN*HIDN
static constexpr float QSCALE = 0.08838834764831845f;  // 128^-0.5

typedef __bf16 bf16_t;
typedef short  short8 __attribute__((ext_vector_type(8)));
typedef __bf16 bf16x8 __attribute__((ext_vector_type(8)));
typedef __bf16 bf16x4 __attribute__((ext_vector_type(4)));
typedef float  f32x4  __attribute__((ext_vector_type(4)));

// XOR-swizzled LDS layouts (16B chunk granularity, bijective per row):
// [r][128] (16 chunks/row): element (r,c) -> r*128 + (((c>>3)^r)&15)*8 + (c&7)
__device__ __forceinline__ int swz16(int r, int c) {
  return r * 128 + ((((c >> 3) ^ r) & 15) << 3) + (c & 7);
}
__device__ __forceinline__ int swz16c(int r, int ch) {  // chunk-aligned (frag)
  return r * 128 + (((ch ^ r) & 15) << 3);
}
// [r][64] (8 chunks/row)
__device__ __forceinline__ int swz8(int r, int c) {
  return r * 64 + ((((c >> 3) ^ r) & 7) << 3) + (c & 7);
}
__device__ __forceinline__ int swz8c(int r, int ch) {
  return r * 64 + (((ch ^ r) & 7) << 3);
}

__device__ __forceinline__ void gload_lds16(const void* g, void* l) {
  __builtin_amdgcn_global_load_lds(
      (__attribute__((address_space(1))) unsigned int*)g,
      (__attribute__((address_space(3))) unsigned int*)l, 16, 0, 0);
}

// ---------------------------------------------------------------------------
// bf16 MFMA GEMM body (m97 structure): C[4096,2048] = A @ Bw^T
// epi: 0 bf16 store, 1 gate (bias + logsigmoid/16 clamp), 2 fp32 store
// ---------------------------------------------------------------------------
__device__ __forceinline__ void gemm_body(const bf16_t* __restrict__ A,
                                          const bf16_t* __restrict__ Bw,
                                          const float*  __restrict__ bias,
                                          bf16_t* __restrict__ outb,
                                          float*  __restrict__ outf, int epi) {
  __shared__ bf16_t As[128 * 32];
  __shared__ bf16_t Bs[128 * 32];
  const int tm   = blockIdx.x * 128;
  const int tn   = blockIdx.y * 128;
  const int wave = threadIdx.x >> 6;
  const int lane = threadIdx.x & 63;
  const int wm   = (wave >> 1) * 64;
  const int wn   = (wave & 1) * 64;
  const int qd   = lane >> 4;
  const int l16  = lane & 15;

  const int c0 = (wave * 2 + 0) * 64 + lane;
  const int c1 = (wave * 2 + 1) * 64 + lane;
  const bf16_t* ga0 = A  + (size_t)(tm + (c0 >> 2)) * HIDN + (c0 & 3) * 8;
  const bf16_t* ga1 = A  + (size_t)(tm + (c1 >> 2)) * HIDN + (c1 & 3) * 8;
  const bf16_t* gb0 = Bw + (size_t)(tn + (c0 >> 2)) * HIDN + (c0 & 3) * 8;
  const bf16_t* gb1 = Bw + (size_t)(tn + (c1 >> 2)) * HIDN + (c1 & 3) * 8;
  bf16_t* la0 = &As[(wave * 2 + 0) * 512];
  bf16_t* la1 = &As[(wave * 2 + 1) * 512];
  bf16_t* lb0 = &Bs[(wave * 2 + 0) * 512];
  bf16_t* lb1 = &Bs[(wave * 2 + 1) * 512];

  f32x4 acc[4][4];
#pragma unroll
  for (int i = 0; i < 4; i++)
#pragma unroll
    for (int j = 0; j < 4; j++) acc[i][j] = (f32x4){0.f, 0.f, 0.f, 0.f};

  for (int k0 = 0; k0 < HIDN; k0 += 32) {
    gload_lds16(ga0, la0); gload_lds16(ga1, la1);
    gload_lds16(gb0, lb0); gload_lds16(gb1, lb1);
    ga0 += 32; ga1 += 32; gb0 += 32; gb1 += 32;
    __syncthreads();
    short8 af[4], bfv[4];
#pragma unroll
    for (int t = 0; t < 4; t++)
      af[t] = *(const short8*)&As[(wm + t * 16 + l16) * 32 + qd * 8];
#pragma unroll
    for (int t = 0; t < 4; t++)
      bfv[t] = *(const short8*)&Bs[(wn + t * 16 + l16) * 32 + qd * 8];
#pragma unroll
    for (int i = 0; i < 4; i++)
#pragma unroll
      for (int j = 0; j < 4; j++)
        acc[i][j] = __builtin_amdgcn_mfma_f32_16x16x32_bf16(af[i], bfv[j],
                                                            acc[i][j], 0, 0, 0);
    __syncthreads();
  }

#pragma unroll
  for (int i = 0; i < 4; i++)
#pragma unroll
    for (int j = 0; j < 4; j++)
#pragma unroll
      for (int r = 0; r < 4; r++) {
        const int row = tm + wm + i * 16 + qd * 4 + r;
        const int col = tn + wn + j * 16 + l16;
        float v = acc[i][j][r];
        if (epi == 1) {
          v += bias[col];
          const float ls = fminf(v, 0.f) - log1pf(__expf(-fabsf(v)));
          v = fmaxf(ls * 0.0625f, -50.f);
        }
        if (epi == 2) outf[(size_t)row * HIDN + col] = v;
        else          outb[(size_t)row * HIDN + col] = (bf16_t)v;
      }
}

// Fused 5-way projection GEMM: z -> {Q,K,V,G1,G2}
__global__ __launch_bounds__(256) void k_gemm_proj(
    const bf16_t* __restrict__ Xb,
    const bf16_t* __restrict__ W0, const bf16_t* __restrict__ W1,
    const bf16_t* __restrict__ W2, const bf16_t* __restrict__ W3,
    const bf16_t* __restrict__ W4,
    const float* __restrict__ bg1, const float* __restrict__ bg2,
    bf16_t* __restrict__ Qb, bf16_t* __restrict__ Kb, bf16_t* __restrict__ Vb,
    bf16_t* __restrict__ G1b, bf16_t* __restrict__ G2b) {
  const int z = blockIdx.z;
  const bf16_t* Ws[5] = {W0, W1, W2, W3, W4};
  bf16_t* Os[5] = {Qb, Kb, Vb, G1b, G2b};
  const float* bias = (z == 3) ? bg1 : ((z == 4) ? bg2 : nullptr);
  gemm_body(Xb, Ws[z], bias, Os[z], nullptr, (z >= 3) ? 1 : 0);
}

__global__ __launch_bounds__(256) void k_gemm_out(
    const bf16_t* __restrict__ attnB, const bf16_t* __restrict__ Wob,
    float* __restrict__ out) {
  gemm_body(attnB, Wob, nullptr, nullptr, out, 2);
}

// ---------------------------------------------------------------------------
// Batched fp32->bf16 converts: y=0 X -> Xb; y=1..4 Wq..Wg1 -> d_out; y=5 Wg2
// ---------------------------------------------------------------------------
__global__ __launch_bounds__(256) void k_cvt_all(
    const float* __restrict__ hid, const float* __restrict__ wq,
    const float* __restrict__ wk, const float* __restrict__ wv,
    const float* __restrict__ wg1, const float* __restrict__ wg2,
    bf16_t* __restrict__ Xb, bf16_t* __restrict__ Wout,
    bf16_t* __restrict__ Wcur) {
  const int y = blockIdx.y;
  const float* srcs[6] = {hid, wq, wk, wv, wg1, wg2};
  bf16_t* dsts[6] = {Xb, Wout, Wout + WELC, Wout + 2 * WELC, Wout + 3 * WELC,
                     Wcur};
  const int n = (y == 0) ? NELC : WELC;
  const float* src = srcs[y];
  bf16_t* dst = dsts[y];
  const int idx = (blockIdx.x * 256 + threadIdx.x) * 4;
  if (idx < n) {
    const float4 f = *(const float4*)(src + idx);
    bf16x4 o;
    o[0] = (bf16_t)f.x; o[1] = (bf16_t)f.y; o[2] = (bf16_t)f.z; o[3] = (bf16_t)f.w;
    *(bf16x4*)(dst + idx) = o;
  }
}

__global__ __launch_bounds__(256) void k_cvt(const float* __restrict__ src,
                                             bf16_t* __restrict__ dst, int n) {
  const int idx = (blockIdx.x * 256 + threadIdx.x) * 4;
  if (idx < n) {
    const float4 f = *(const float4*)(src + idx);
    bf16x4 o;
    o[0] = (bf16_t)f.x; o[1] = (bf16_t)f.y; o[2] = (bf16_t)f.z; o[3] = (bf16_t)f.w;
    *(bf16x4*)(dst + idx) = o;
  }
}

__global__ __launch_bounds__(256) void k_zero(float* __restrict__ out) {
  out[(size_t)blockIdx.x * 256 + threadIdx.x] = 0.f;
}

// ---------------------------------------------------------------------------
// S1 (MFMA): UT[dv][dk] = sum_s V[s][dv] * Khat[s][dk]   (Khat = k*exp(B-b))
// waves 0-1: gate cumsum + khT build; waves 2-3: V transpose into vT.
// ---------------------------------------------------------------------------
__global__ __launch_bounds__(256) void k_s1(
    const bf16_t* __restrict__ Kb, const bf16_t* __restrict__ Vb,
    const bf16_t* __restrict__ G, bf16_t* __restrict__ UT,
    float* __restrict__ Btot) {
  const int n = blockIdx.x, bh = blockIdx.y;
  const int b = bh >> 4, h = bh & 15;
  const int tid = threadIdx.x;
  __shared__ bf16_t vT[128 * 64];   // [dv][s] swz8
  __shared__ bf16_t khT[128 * 64];  // [dk][s] swz8
  const size_t base = ((size_t)(b * SEQ + n * CHUNK)) * HIDN + h * DD;

  if (tid < DD) {
    const int d = tid;
    float c = 0.f;
    for (int t = 0; t < CHUNK; t++) c += (float)G[base + (size_t)t * HIDN + d];
    const float Bt = c;
    Btot[((size_t)bh * NCHUNK + n) * DD + d] = Bt;
    c = 0.f;
    for (int t = 0; t < CHUNK; t++) {
      c += (float)G[base + (size_t)t * HIDN + d];
      khT[swz8(d, t)] =
          (bf16_t)((float)Kb[base + (size_t)t * HIDN + d] * __expf(Bt - c));
    }
  } else {
    const int t2 = tid - 128;
    for (int i = t2; i < CHUNK * DD; i += 128) {
      const int t = i >> 7, d = i & 127;
      vT[swz8(d, t)] = Vb[base + (size_t)t * HIDN + d];
    }
  }
  __syncthreads();

  const int wave = tid >> 6, lane = tid & 63, qd = lane >> 4, l16 = lane & 15;
  const int m0 = (wave >> 1) * 64;  // dv half
  const int n0 = (wave & 1) * 64;   // dk half
  f32x4 acc[4][4];
#pragma unroll
  for (int i = 0; i < 4; i++)
#pragma unroll
    for (int j = 0; j < 4; j++) acc[i][j] = (f32x4){0.f, 0.f, 0.f, 0.f};
#pragma unroll
  for (int ks = 0; ks < 2; ks++) {
    const int ch = ks * 4 + qd;
    short8 af[4], bfv[4];
#pragma unroll
    for (int i = 0; i < 4; i++)
      af[i] = *(const short8*)&vT[swz8c(m0 + i * 16 + l16, ch)];
#pragma unroll
    for (int j = 0; j < 4; j++)
      bfv[j] = *(const short8*)&khT[swz8c(n0 + j * 16 + l16, ch)];
#pragma unroll
    for (int i = 0; i < 4; i++)
#pragma unroll
      for (int j = 0; j < 4; j++)
        acc[i][j] = __builtin_amdgcn_mfma_f32_16x16x32_bf16(af[i], bfv[j],
                                                            acc[i][j], 0, 0, 0);
  }
  bf16_t* Uo = UT + ((size_t)bh * NCHUNK + n) * (size_t)(DD * DD);
#pragma unroll
  for (int i = 0; i < 4; i++)
#pragma unroll
    for (int j = 0; j < 4; j++)
#pragma unroll
      for (int r = 0; r < 4; r++)
        Uo[(size_t)(m0 + i * 16 + qd * 4 + r) * DD + n0 + j * 16 + l16] =
            (bf16_t)acc[i][j][r];
}

// ---------------------------------------------------------------------------
// S2: sequential chunk combine on UT ([dv][dk], decay exp(B[dk]) on fast axis)
// stores S^T (state BEFORE chunk n) in place.
// ---------------------------------------------------------------------------
__global__ __launch_bounds__(256) void k_s2(bf16_t* __restrict__ UT,
                                            const float* __restrict__ Btot) {
  const int dg = blockIdx.x, bh = blockIdx.y;
  const int dv = dg * 8 + (threadIdx.x >> 5);
  const int dk0 = (threadIdx.x & 31) * 4;
  float st[4] = {0.f, 0.f, 0.f, 0.f};
  for (int nn = 0; nn < NCHUNK; nn++) {
    bf16_t* p =
        UT + ((size_t)bh * NCHUNK + nn) * (size_t)(DD * DD) + dv * DD + dk0;
    const float4 bp =
        *(const float4*)(Btot + ((size_t)bh * NCHUNK + nn) * DD + dk0);
    const bf16x4 u = *(const bf16x4*)p;
    bf16x4 sv;
#pragma unroll
    for (int j = 0; j < 4; j++) sv[j] = (bf16_t)st[j];
    *(bf16x4*)p = sv;
    st[0] = st[0] * __expf(bp.x) + (float)u[0];
    st[1] = st[1] * __expf(bp.y) + (float)u[1];
    st[2] = st[2] * __expf(bp.z) + (float)u[2];
    st[3] = st[3] * __expf(bp.w) + (float)u[3];
  }
}

// ---------------------------------------------------------------------------
// S3 (MFMA, fused intra+inter):
//   P[t][s] = (qh2 . k2) masked causal;  O = P@V + qh2@S  -> attn (w_e folded)
// qh2 = q*w*scale*exp(b); k2 = k*exp(-b); S^T read from UT as global B-frags.
// ---------------------------------------------------------------------------
template <int ACC>
__global__ __launch_bounds__(256) void k_s3(
    const bf16_t* __restrict__ Qb, const bf16_t* __restrict__ Kb,
    const bf16_t* __restrict__ Vb, const bf16_t* __restrict__ G,
    const bf16_t* __restrict__ UT, const float* __restrict__ alpha,
    bf16_t* __restrict__ attn) {
  const int n = blockIdx.x, bh = blockIdx.y;
  const int b = bh >> 4, h = bh & 15;
  const int tid = threadIdx.x;
  __shared__ bf16_t qh2[64 * 128];  // [t][d] swz16
  __shared__ bf16_t k2v[64 * 128];  // [s][d] swz16; reused as vT [dv][s] swz8
  __shared__ bf16_t Ps[64 * 64];    // [t][s] swz8
  const size_t base = ((size_t)(b * SEQ + n * CHUNK)) * HIDN + h * DD;
  const float mx = fmaxf(alpha[0], alpha[1]);
  const float x0 = __expf(alpha[0] - mx), x1 = __expf(alpha[1] - mx);
  const float w = (ACC ? x1 : x0) / (x0 + x1);

  if (tid < DD) {
    const int d = tid;
    const float wsc = w * QSCALE;
    float c = 0.f;
    for (int t = 0; t < CHUNK; t++) {
      c += (float)G[base + (size_t)t * HIDN + d];
      const float ec = __expf(c);
      qh2[swz16(t, d)] =
          (bf16_t)((float)Qb[base + (size_t)t * HIDN + d] * wsc * ec);
      k2v[swz16(t, d)] =
          (bf16_t)((float)Kb[base + (size_t)t * HIDN + d] * __expf(-c));
    }
  }
  __syncthreads();

  const int wave = tid >> 6, lane = tid & 63, qd = lane >> 4, l16 = lane & 15;
  {  // P: M=t(64) N=s(64) K=d(128); wave owns t-rows [wave*16, wave*16+16)
    f32x4 pacc[4];
#pragma unroll
    for (int j = 0; j < 4; j++) pacc[j] = (f32x4){0.f, 0.f, 0.f, 0.f};
#pragma unroll
    for (int ks = 0; ks < 4; ks++) {
      const int ch = ks * 4 + qd;
      const short8 a = *(const short8*)&qh2[swz16c(wave * 16 + l16, ch)];
#pragma unroll
      for (int j = 0; j < 4; j++) {
        const short8 bq = *(const short8*)&k2v[swz16c(j * 16 + l16, ch)];
        pacc[j] = __builtin_amdgcn_mfma_f32_16x16x32_bf16(a, bq, pacc[j], 0, 0, 0);
      }
    }
#pragma unroll
    for (int j = 0; j < 4; j++)
#pragma unroll
      for (int r = 0; r < 4; r++) {
        const int t = wave * 16 + qd * 4 + r, s = j * 16 + l16;
        Ps[swz8(t, s)] = (t >= s) ? (bf16_t)pacc[j][r] : (bf16_t)0.f;
      }
  }
  __syncthreads();
  // rebuild k2v region as vT [dv][s]
  for (int i = tid; i < CHUNK * DD; i += 256) {
    const int t = i >> 7, d = i & 127;
    k2v[swz8(d, t)] = Vb[base + (size_t)t * HIDN + d];
  }
  __syncthreads();

  // O = Ps@vT + qh2@S : M=t(64) N=dv(128); wave owns dv cols [wave*32,+32)
  const bf16_t* Sp = UT + ((size_t)bh * NCHUNK + n) * (size_t)(DD * DD);
  const int nw = wave * 32;
  f32x4 acc[4][2];
#pragma unroll
  for (int i = 0; i < 4; i++)
#pragma unroll
    for (int j = 0; j < 2; j++) acc[i][j] = (f32x4){0.f, 0.f, 0.f, 0.f};
#pragma unroll
  for (int ks = 0; ks < 2; ks++) {  // intra: K = s (64)
    const int ch = ks * 4 + qd;
    short8 a[4];
#pragma unroll
    for (int i = 0; i < 4; i++)
      a[i] = *(const short8*)&Ps[swz8c(i * 16 + l16, ch)];
#pragma unroll
    for (int j = 0; j < 2; j++) {
      const short8 bq = *(const short8*)&k2v[swz8c(nw + j * 16 + l16, ch)];
#pragma unroll
      for (int i = 0; i < 4; i++)
        acc[i][j] = __builtin_amdgcn_mfma_f32_16x16x32_bf16(a[i], bq,
                                                            acc[i][j], 0, 0, 0);
    }
  }
#pragma unroll
  for (int ks = 0; ks < 4; ks++) {  // inter: K = d (128), B-frags from global
    const int ch = ks * 4 + qd;
    short8 a[4];
#pragma unroll
    for (int i = 0; i < 4; i++)
      a[i] = *(const short8*)&qh2[swz16c(i * 16 + l16, ch)];
#pragma unroll
    for (int j = 0; j < 2; j++) {
      const short8 bq =
          *(const short8*)(Sp + (size_t)(nw + j * 16 + l16) * DD + ks * 32 + qd * 8);
#pragma unroll
      for (int i = 0; i < 4; i++)
        acc[i][j] = __builtin_amdgcn_mfma_f32_16x16x32_bf16(a[i], bq,
                                                            acc[i][j], 0, 0, 0);
    }
  }
#pragma unroll
  for (int i = 0; i < 4; i++)
#pragma unroll
    for (int j = 0; j < 2; j++)
#pragma unroll
      for (int r = 0; r < 4; r++) {
        const int t = i * 16 + qd * 4 + r;
        const int dv = nw + j * 16 + l16;
        bf16_t* p = &attn[base + (size_t)t * HIDN + dv];
        if (ACC) *p = (bf16_t)((float)*p + acc[i][j][r]);
        else     *p = (bf16_t)acc[i][j][r];
      }
}

// ---------------------------------------------------------------------------
extern "C" void kernel_launch(void* const* d_in, const int* in_sizes, int n_in,
                              void* d_out, int out_size, void* d_ws,
                              size_t ws_size, hipStream_t stream) {
  const float* hid  = (const float*)d_in[0];
  const float* wq   = (const float*)d_in[1];
  const float* wk   = (const float*)d_in[2];
  const float* wv   = (const float*)d_in[3];
  const float* wo   = (const float*)d_in[4];
  const float* wg1  = (const float*)d_in[5];
  const float* bg1  = (const float*)d_in[6];
  const float* wg2  = (const float*)d_in[7];
  const float* bg2  = (const float*)d_in[8];
  const float* alph = (const float*)d_in[9];
  float* out = (float*)d_out;
  (void)in_sizes; (void)n_in; (void)out_size;

  char* ws = (char*)d_ws;
  size_t off = 0;
  auto alloc = [&](size_t bytes) -> void* {
    void* p = ws + off;
    off += (bytes + 255) & ~(size_t)255;
    return p;
  };
  const size_t NEL = NELC, WEL = WELC;
  bf16_t* Xb   = (bf16_t*)alloc(NEL * 2);  // X bf16; reused as attn later
  bf16_t* Wcur = (bf16_t*)alloc(WEL * 2);  // Wg2, later Wo
  bf16_t* Qb   = (bf16_t*)alloc(NEL * 2);
  bf16_t* Kb   = (bf16_t*)alloc(NEL * 2);
  bf16_t* Vb   = (bf16_t*)alloc(NEL * 2);
  bf16_t* G1b  = (bf16_t*)alloc(NEL * 2);
  bf16_t* G2b  = (bf16_t*)alloc(NEL * 2);
  float*  Btot = (float*) alloc((size_t)NBH * NCHUNK * DD * 4);
  // d_out (33,554,432 B) double-duty: 4 bf16 weights (exactly) before scans,
  // then U/S chunk states, then the final fp32 output.
  bf16_t* Wd = (bf16_t*)d_out;
  bf16_t* UT = (bf16_t*)d_out;

  if (off > ws_size) {  // diagnostic fallback: fail cleanly (absmax=ref max)
    k_zero<<<dim3((unsigned)(NEL / 256)), 256, 0, stream>>>(out);
    return;
  }

  k_cvt_all<<<dim3(8192, 6), 256, 0, stream>>>(hid, wq, wk, wv, wg1, wg2, Xb,
                                               Wd, Wcur);
  k_gemm_proj<<<dim3(32, 16, 5), 256, 0, stream>>>(
      Xb, Wd, Wd + WEL, Wd + 2 * WEL, Wd + 3 * WEL, Wcur, bg1, bg2, Qb, Kb, Vb,
      G1b, G2b);

  const dim3 gs(NCHUNK, NBH), g2(16, NBH);
  // e = 0
  k_s1<<<gs, 256, 0, stream>>>(Kb, Vb, G1b, UT, Btot);
  k_s2<<<g2, 256, 0, stream>>>(UT, Btot);
  k_s3<0><<<gs, 256, 0, stream>>>(Qb, Kb, Vb, G1b, UT, alph, Xb);
  // e = 1
  k_s1<<<gs, 256, 0, stream>>>(Kb, Vb, G2b, UT, Btot);
  k_s2<<<g2, 256, 0, stream>>>(UT, Btot);
  k_s3<1><<<gs, 256, 0, stream>>>(Qb, Kb, Vb, G2b, UT, alph, Xb);

  k_cvt<<<4096, 256, 0, stream>>>(wo, Wcur, (int)WEL);
  k_gemm_out<<<dim3(32, 16), 256, 0, stream>>>(Xb, Wcur, out);
}